// Round 11
// baseline (227.249 us; speedup 1.0000x reference)
//
#include <hip/hip_runtime.h>
#include <stdint.h>
#include <math.h>

#define N_PTS 4096
#define DIM   512
#define KM1   7
#define NDRAW (N_PTS * KM1)     // 28672
#define MASKW (N_PTS / 32)      // 128 words per row
#define NP    ((size_t)N_PTS * DIM)
#define REFCAP (1u << 18)       // refine-list capacity (1 MB)

typedef __attribute__((ext_vector_type(8))) short bf16x8;
typedef __attribute__((ext_vector_type(4))) float f32x4;

// ---------------- threefry2x32, key = (0, 42), JAX partitionable bits ----------------
__device__ __forceinline__ uint32_t rotl32(uint32_t x, uint32_t r) {
  return (x << r) | (x >> (32u - r));
}

__device__ __forceinline__ uint32_t threefry_bits(uint32_t x0, uint32_t x1) {
  const uint32_t ks0 = 0u, ks1 = 42u, ks2 = (0u ^ 42u ^ 0x1BD11BDAu);
  x0 += ks0; x1 += ks1;
#define TFR(r) { x0 += x1; x1 = rotl32(x1, r); x1 ^= x0; }
  TFR(13u) TFR(15u) TFR(26u) TFR(6u)   x0 += ks1; x1 += ks2 + 1u;
  TFR(17u) TFR(29u) TFR(16u) TFR(24u)  x0 += ks2; x1 += ks0 + 2u;
  TFR(13u) TFR(15u) TFR(26u) TFR(6u)   x0 += ks0; x1 += ks1 + 3u;
  TFR(17u) TFR(29u) TFR(16u) TFR(24u)  x0 += ks1; x1 += ks2 + 4u;
  TFR(13u) TFR(15u) TFR(26u) TFR(6u)   x0 += ks2; x1 += ks0 + 5u;
#undef TFR
  return x0 ^ x1;   // partitionable 32-bit: out0 ^ out1
}

__device__ __forceinline__ ushort bf16rn(float f) {
  uint32_t u = __float_as_uint(f);
  uint32_t r = (u + 0x7FFFu + ((u >> 16) & 1u)) >> 16;
  return (ushort)r;
}

// ---------------- kernel A: per-row split into 2 bf16 planes (hi, mid) + sq ----------------
__global__ __launch_bounds__(64) void split_kernel(const float* __restrict__ x,
                                                   ushort* __restrict__ xs,
                                                   float* __restrict__ sq,
                                                   uint32_t* __restrict__ refcnt) {
  const int i = blockIdx.x;
  const int t = threadIdx.x;
  if (i == 0 && t == 0) *refcnt = 0u;
  const float4* row4 = (const float4*)(x + (size_t)i * DIM);
  float4 u = row4[2 * t], v = row4[2 * t + 1];
  float a[8] = {u.x, u.y, u.z, u.w, v.x, v.y, v.z, v.w};

  double s = 0.0;
#pragma unroll
  for (int j = 0; j < 8; ++j) s += (double)a[j] * (double)a[j];
#pragma unroll
  for (int off = 32; off > 0; off >>= 1) s += __shfl_down(s, off, 64);
  if (t == 0) sq[i] = (float)s;

  ushort h[8], m8[8];
#pragma unroll
  for (int j = 0; j < 8; ++j) {
    float f = a[j];
    ushort hb = bf16rn(f);
    float hf = __uint_as_float(((uint32_t)hb) << 16);
    float r1 = f - hf;                 // exact in f32
    h[j] = hb; m8[j] = bf16rn(r1);
  }
  const int q = i * 128 + t * 2;
  ((ushort4*)xs)[q]            = (ushort4){h[0], h[1], h[2], h[3]};
  ((ushort4*)xs)[q + 1]        = (ushort4){h[4], h[5], h[6], h[7]};
  ((ushort4*)(xs + NP))[q]     = (ushort4){m8[0], m8[1], m8[2], m8[3]};
  ((ushort4*)(xs + NP))[q + 1] = (ushort4){m8[4], m8[5], m8[6], m8[7]};
}

// ---------------- kernel 1: upper-triangle mask; 3-product (hh+hm+mh) MFMA Gram + band flag ----------------
// Hard bound on dropped terms (hl+lh+mm+...) <= 1.2e-5 on dot => 2.4e-5 on dist2. Pairs with
// |dist2-1.96| < 6e-5 are exactly re-decided by refine_kernel (f64). Outside the band the
// 3-product sign of (d<1.4) provably matches numpy.
#define BK 32
#define NTILES (DIM / BK)   // 16

__device__ __forceinline__ void gload_lds16(const ushort* g, ushort* l) {
  __builtin_amdgcn_global_load_lds((__attribute__((address_space(1))) void*)(ushort*)g,
                                   (__attribute__((address_space(3))) void*)l, 16, 0, 0);
}

__global__ __launch_bounds__(256) void gram_kernel(const ushort* __restrict__ xs,
                                                   const float* __restrict__ sq,
                                                   uint32_t* __restrict__ mask,
                                                   uint32_t* __restrict__ reflist,
                                                   uint32_t* __restrict__ refcnt) {
  __shared__ __align__(1024) ushort SA[2][128 * BK];   // 16 KB
  __shared__ __align__(1024) ushort SB[2][64 * BK];    // 8 KB
  __shared__ uint32_t smask[128][2];                   // 1 KB

  // XCD-aware bijective swizzle: 1056 = 8 x 132
  const int tblk = (blockIdx.x & 7) * 132 + (blockIdx.x >> 3);
  // block map: tblk -> (bi, cj): row-panel bi (128 rows), col-panel cj (64 cols), cj >= 2*bi
  int bi = (int)((65.0 - sqrt(4225.0 - 4.0 * (double)tblk)) * 0.5);
  while ((bi + 1) * (65 - (bi + 1)) <= tblk) ++bi;
  while (bi * (65 - bi) > tblk) --bi;
  const int cj = 2 * bi + (tblk - bi * (65 - bi));
  const int i0 = bi * 128, c0 = cj * 64;

  const int tid = threadIdx.x;
  const int w = tid >> 6, l = tid & 63;
  const int wr = w >> 1, wc = w & 1;               // wave covers 64x32 output

  ((uint32_t*)smask)[tid] = 0u;                    // 256 words exactly

  f32x4 acc[4][2] = {};

  // staging: A-plane tile 8KB -> wave w bytes [w*2048,+2048); B-plane tile 4KB -> [w*1024,+1024).
  // LDS dest linear; bank swizzle via pre-swizzled GLOBAL source column:
  // phys slot s (16B) of row r holds logical k-block s ^ ((r>>1)&3).
  const int rowA = w * 32 + (l >> 2);
  const int rowB = w * 16 + (l >> 2);
  const int e0 = (((l & 3) ^ ((l >> 3) & 3)) << 3);   // swizzled source col (ushorts)
  const ushort* asrc = xs + (size_t)(i0 + rowA) * DIM + e0;
  const ushort* bsrc = xs + (size_t)(c0 + rowB) * DIM + e0;

  // frag read offsets (ushort units): slot = (l>>4) ^ ((row>>1)&3)
  const int sl = (((l >> 4) ^ ((l >> 1) & 3)) << 3);
  const int abase = (wr * 64 + (l & 15)) * BK + sl;
  const int bbase = (wc * 32 + (l & 15)) * BK + sl;

#define STAGE(k0) { \
  _Pragma("unroll") for (int p_ = 0; p_ < 2; ++p_) { \
    const ushort* ap_ = asrc + (size_t)p_ * NP + (k0); \
    gload_lds16(ap_,            &SA[p_][w * 1024]); \
    gload_lds16(ap_ + 16 * DIM, &SA[p_][w * 1024 + 512]); \
    gload_lds16(bsrc + (size_t)p_ * NP + (k0), &SB[p_][w * 512]); } }

#define RDA(frag, p) { \
  _Pragma("unroll") for (int q_ = 0; q_ < 4; ++q_) \
    frag[q_] = *(const bf16x8*)(&SA[p][abase + q_ * 16 * BK]); }

#define RDB(frag, p) { \
  _Pragma("unroll") for (int q_ = 0; q_ < 2; ++q_) \
    frag[q_] = *(const bf16x8*)(&SB[p][bbase + q_ * 16 * BK]); }

#define MM(A_, B_) { \
  _Pragma("unroll") for (int m_ = 0; m_ < 4; ++m_) \
  _Pragma("unroll") for (int n_ = 0; n_ < 2; ++n_) \
    acc[m_][n_] = __builtin_amdgcn_mfma_f32_16x16x32_bf16(A_[m_], B_[n_], acc[m_][n_], 0, 0, 0); }

  STAGE(0);
#pragma unroll 1
  for (int ks = 0; ks < NTILES; ++ks) {
    __syncthreads();                      // drains vmcnt(0): STAGE(ks) landed in LDS
    bf16x8 a0[4], a1[4], b0[2], b1[2];
    // per-element accumulation order: hh, hm, mh (ks-interleaved)
    RDA(a0, 0); RDB(b0, 0);
    MM(a0, b0);
    RDB(b1, 1);
    MM(a0, b1);
    RDA(a1, 1);
    __syncthreads();                      // all waves' LDS reads done; LDS reusable
    if (ks + 1 < NTILES) STAGE((ks + 1) * BK);   // overwrite under the last 8 MFMAs
    MM(a1, b0);
  }
#undef STAGE
#undef RDA
#undef RDB
#undef MM

  __syncthreads();

  // epilogue: dist2 -> provisional validity bits + band flags
#pragma unroll
  for (int m = 0; m < 4; ++m) {
    const int gi_base = i0 + wr * 64 + m * 16;
#pragma unroll
    for (int n = 0; n < 2; ++n) {
      const int gc = c0 + wc * 32 + n * 16 + (l & 15);
      const float sqc = sq[gc];
#pragma unroll
      for (int reg = 0; reg < 4; ++reg) {
        const int gi = gi_base + (l >> 4) * 4 + reg;
        float dot = acc[m][n][reg];
        float tsum = sq[gi] + sqc;
        float dist2 = tsum - 2.0f * dot;
        float d = sqrtf(dist2);
        bool diffblk = ((gi >> 3) != (gc >> 3));
        bool v = (d < 1.4f) && diffblk;
        if (diffblk && fabsf(dist2 - 1.96f) < 6e-5f) {
          uint32_t idx = atomicAdd(refcnt, 1u);
          if (idx < REFCAP) reflist[idx] = ((uint32_t)gi << 16) | (uint32_t)gc;
        }
        unsigned long long b = __ballot(v);
        if (l < 4) {
          uint32_t chunk = (uint32_t)((b >> (16 * l)) & 0xFFFFull);
          int rowL = wr * 64 + m * 16 + 4 * l + reg;
          atomicOr(&smask[rowL][wc], chunk << (16 * n));
        }
      }
    }
  }
  __syncthreads();
  {
    int row = tid >> 1, wrd = tid & 1;
    mask[(size_t)(i0 + row) * MASKW + cj * 2 + wrd] = smask[row][wrd];
  }
}

// ---------------- kernel 1a: f64 exact re-decision of band pairs ----------------
__global__ __launch_bounds__(256) void refine_kernel(const float* __restrict__ x,
                                                     const float* __restrict__ sq,
                                                     const uint32_t* __restrict__ reflist,
                                                     const uint32_t* __restrict__ refcnt,
                                                     uint32_t* __restrict__ mask) {
  const int wid = (blockIdx.x * 256 + threadIdx.x) >> 6;
  const int nwv = (gridDim.x * 256) >> 6;
  const int l = threadIdx.x & 63;
  uint32_t n = *refcnt; if (n > REFCAP) n = REFCAP;
  for (uint32_t e = wid; e < n; e += nwv) {
    const uint32_t pk = reflist[e];
    const int gi = pk >> 16, gc = pk & 0xFFFF;
    const float4* xi = (const float4*)(x + (size_t)gi * DIM) + l * 2;
    const float4* xc = (const float4*)(x + (size_t)gc * DIM) + l * 2;
    float4 u0 = xi[0], u1 = xi[1], v0 = xc[0], v1 = xc[1];
    double s = (double)u0.x * v0.x + (double)u0.y * v0.y + (double)u0.z * v0.z + (double)u0.w * v0.w
             + (double)u1.x * v1.x + (double)u1.y * v1.y + (double)u1.z * v1.z + (double)u1.w * v1.w;
#pragma unroll
    for (int off = 32; off > 0; off >>= 1) s += __shfl_down(s, off, 64);
    if (l == 0) {
      float dot = (float)s;
      float tsum = sq[gi] + sq[gc];
      float dist2 = tsum - 2.0f * dot;
      float d = sqrtf(dist2);
      uint32_t* wptr = mask + (size_t)gi * MASKW + (gc >> 5);
      uint32_t bit = 1u << (gc & 31);
      if (d < 1.4f) atomicOr(wptr, bit); else atomicAnd(wptr, ~bit);
    }
  }
}

// ---------------- kernel 1b: mirror upper-triangle mask blocks to lower triangle ----------------
__global__ __launch_bounds__(256) void mirror_kernel(uint32_t* __restrict__ mask) {
  const int t = blockIdx.x;                     // 0..495 : pairs bi < bj (128-blocks)
  int bi = (int)((63.0 - sqrt(3969.0 - 8.0 * (double)t)) * 0.5);
  while ((63 * (bi + 1) - (bi + 1) * (bi + 1)) / 2 <= t) ++bi;
  while ((63 * bi - bi * bi) / 2 > t) --bi;
  const int bj = bi + 1 + (t - (63 * bi - bi * bi) / 2);

  const int grp = threadIdx.x >> 5;             // 8 groups of 32 lanes
  const int lane = threadIdx.x & 31;

  for (int sb = grp; sb < 16; sb += 8) {
    const int sr = sb >> 2, sc = sb & 3;
    uint32_t x = mask[(size_t)(bi * 128 + sr * 32 + lane) * MASKW + bj * 4 + sc];
    uint32_t m = 0x0000FFFFu;
#pragma unroll
    for (int s = 16; s; s >>= 1) {
      uint32_t y = (uint32_t)__shfl_xor((int)x, s, 64);
      x = (lane & s) ? (((y >> s) & m) | (x & ~m))
                     : ((x & m) | ((y & m) << s));
      m ^= (m << (s >> 1));
    }
    mask[(size_t)(bj * 128 + sc * 32 + lane) * MASKW + bi * 4 + sr] = x;
  }
}

// ---------------- kernel 2: one block per row; compact valid list, 7 j-inner argmax draws ----------------
__global__ __launch_bounds__(256) void sample_kernel(const uint32_t* __restrict__ mask,
                                                     int* __restrict__ nidx) {
  const int i = blockIdx.x;
  const int t = threadIdx.x;
  const int w = t >> 6, l = t & 63;

  __shared__ uint32_t m[MASKW];
  __shared__ int cnt[MASKW];
  __shared__ ushort clist[N_PTS];
  __shared__ unsigned long long red[4][KM1];

  if (t < MASKW) m[t] = mask[(size_t)i * MASKW + t];
  __syncthreads();

  if (t < MASKW) cnt[t] = __popc(m[t]);
  __syncthreads();
  for (int s = 1; s < MASKW; s <<= 1) {
    int v = 0;
    if (t < MASKW) { v = cnt[t]; if (t >= s) v += cnt[t - s]; }
    __syncthreads();
    if (t < MASKW) cnt[t] = v;
    __syncthreads();
  }
  if (t < MASKW) {
    uint32_t mw = m[t];
    int off = cnt[t] - __popc(mw);
    int base_c = t << 5;
    while (mw) {
      int b = __ffs(mw) - 1;
      mw &= mw - 1;
      clist[off++] = (ushort)(base_c + b);
    }
  }
  __syncthreads();
  const int n = cnt[MASKW - 1];

  unsigned long long best[KM1];
#pragma unroll
  for (int j = 0; j < KM1; ++j) best[j] = 0ull;

  if (n > 0) {
    for (int q = t; q < n; q += 256) {
      const uint32_t c = clist[q];
#pragma unroll
      for (int j = 0; j < KM1; ++j) {
        const uint32_t ctr = ((uint32_t)(((j << 12) + i)) << 12) + c;   // r*4096+c
        uint32_t key = threefry_bits(0u, ctr) >> 9;
        unsigned long long p = ((unsigned long long)key << 12) | (unsigned long long)(4095u - c);
        if (p > best[j]) best[j] = p;
      }
    }
  } else {
    for (int c = t; c < N_PTS; c += 256) {
#pragma unroll
      for (int j = 0; j < KM1; ++j) {
        const uint32_t ctr = ((uint32_t)(((j << 12) + i)) << 12) + (uint32_t)c;
        uint32_t key = threefry_bits(0u, ctr) >> 9;
        unsigned long long p = ((unsigned long long)key << 12) | (unsigned long long)(4095u - c);
        if (p > best[j]) best[j] = p;
      }
    }
  }

#pragma unroll
  for (int j = 0; j < KM1; ++j) {
    unsigned long long b = best[j];
#pragma unroll
    for (int off = 32; off > 0; off >>= 1) {
      unsigned long long o = __shfl_down(b, off, 64);
      if (o > b) b = o;
    }
    if (l == 0) red[w][j] = b;
  }
  __syncthreads();
  if (t < KM1) {
    unsigned long long b = red[0][t];
#pragma unroll
    for (int wv = 1; wv < 4; ++wv) if (red[wv][t] > b) b = red[wv][t];
    nidx[i * KM1 + t] = 4095 - (int)(b & 0xFFFull);
  }
}

// ---------------- kernel 3: assemble (a_idx, x[a], x[p], x[n], x) ----------------
__global__ __launch_bounds__(256) void assemble_kernel(const float* __restrict__ x,
                                                       const int* __restrict__ nidx,
                                                       float* __restrict__ out) {
  const int B1 = 7168;
  const int SEC = NDRAW * (DIM / 4);
  const int B2 = B1 + SEC;
  const int B3 = B2 + SEC;
  const int B4 = B3 + SEC;
  const int TOT = B4 + N_PTS * (DIM / 4);

  const f32x4* x4 = (const f32x4*)x;
  f32x4* o4 = (f32x4*)out;

  for (int q = blockIdx.x * blockDim.x + threadIdx.x; q < TOT;
       q += gridDim.x * blockDim.x) {
    f32x4 v;
    if (q < B1) {
      int e = q * 4;
      v = (f32x4){(float)((e + 0) / KM1), (float)((e + 1) / KM1),
                  (float)((e + 2) / KM1), (float)((e + 3) / KM1)};
    } else {
      int src, rem;
      if (q < B2) {
        rem = q - B1; int tt = rem >> 7; src = tt / KM1;
      } else if (q < B3) {
        rem = q - B2; int tt = rem >> 7; int i = tt / KM1; int mm = tt - i * KM1;
        int s = i & 7; int bs = i & ~7;
        src = bs + mm + (mm >= s ? 1 : 0);
      } else if (q < B4) {
        rem = q - B3; int tt = rem >> 7; src = nidx[tt];
      } else {
        rem = q - B4; src = rem >> 7;
      }
      int col = rem & 127;
      v = x4[(size_t)src * (DIM / 4) + col];
    }
    o4[q] = v;
  }
}

// ---------------- launch ----------------
extern "C" void kernel_launch(void* const* d_in, const int* in_sizes, int n_in,
                              void* d_out, int out_size, void* d_ws, size_t ws_size,
                              hipStream_t stream) {
  const float* x = (const float*)d_in[0];
  float* out = (float*)d_out;

  uint8_t* ws = (uint8_t*)d_ws;
  uint32_t* mask = (uint32_t*)ws;                                          // 2 MiB
  int* nidx = (int*)(ws + (size_t)N_PTS * MASKW * 4);                      // 112 KiB
  float* sq = (float*)(ws + (size_t)N_PTS * MASKW * 4 + (size_t)NDRAW * 4);// 16 KiB
  uint32_t* refcnt = (uint32_t*)(ws + (size_t)N_PTS * MASKW * 4 + (size_t)NDRAW * 4 + N_PTS * 4);

  // bf16 split planes (2 x 4.2 MB) + refine list live in d_out (185 MB) — overwritten by assemble later
  ushort* xs = (ushort*)d_out;
  uint32_t* reflist = (uint32_t*)((uint8_t*)d_out + (size_t)64 * 1024 * 1024);

  split_kernel<<<N_PTS, 64, 0, stream>>>(x, xs, sq, refcnt);
  gram_kernel<<<1056, 256, 0, stream>>>(xs, sq, mask, reflist, refcnt);
  refine_kernel<<<512, 256, 0, stream>>>(x, sq, reflist, refcnt, mask);
  mirror_kernel<<<496, 256, 0, stream>>>(mask);
  sample_kernel<<<N_PTS, 256, 0, stream>>>(mask, nidx);
  assemble_kernel<<<4096, 256, 0, stream>>>(x, nidx, out);
}

// Round 12
// 161.391 us; speedup vs baseline: 1.4081x; 1.4081x over previous
//
#include <hip/hip_runtime.h>
#include <stdint.h>
#include <math.h>

#define N_PTS 4096
#define DIM   512
#define KM1   7
#define NDRAW (N_PTS * KM1)     // 28672
#define MASKW (N_PTS / 32)      // 128 words per row
#define NP    ((size_t)N_PTS * DIM)

typedef __attribute__((ext_vector_type(8))) short bf16x8;
typedef __attribute__((ext_vector_type(4))) float f32x4;

// ---------------- threefry2x32, key = (0, 42), JAX partitionable bits ----------------
__device__ __forceinline__ uint32_t rotl32(uint32_t x, uint32_t r) {
  return (x << r) | (x >> (32u - r));
}

__device__ __forceinline__ uint32_t threefry_bits(uint32_t x0, uint32_t x1) {
  const uint32_t ks0 = 0u, ks1 = 42u, ks2 = (0u ^ 42u ^ 0x1BD11BDAu);
  x0 += ks0; x1 += ks1;
#define TFR(r) { x0 += x1; x1 = rotl32(x1, r); x1 ^= x0; }
  TFR(13u) TFR(15u) TFR(26u) TFR(6u)   x0 += ks1; x1 += ks2 + 1u;
  TFR(17u) TFR(29u) TFR(16u) TFR(24u)  x0 += ks2; x1 += ks0 + 2u;
  TFR(13u) TFR(15u) TFR(26u) TFR(6u)   x0 += ks0; x1 += ks1 + 3u;
  TFR(17u) TFR(29u) TFR(16u) TFR(24u)  x0 += ks1; x1 += ks2 + 4u;
  TFR(13u) TFR(15u) TFR(26u) TFR(6u)   x0 += ks2; x1 += ks0 + 5u;
#undef TFR
  return x0 ^ x1;   // partitionable 32-bit: out0 ^ out1
}

__device__ __forceinline__ ushort bf16rn(float f) {
  uint32_t u = __float_as_uint(f);
  uint32_t r = (u + 0x7FFFu + ((u >> 16) & 1u)) >> 16;
  return (ushort)r;
}

// ---------------- kernel A: per-row split into 3 bf16 planes + sq (f64 accumulate) ----------------
__global__ __launch_bounds__(64) void split_kernel(const float* __restrict__ x,
                                                   ushort* __restrict__ xs,
                                                   float* __restrict__ sq) {
  const int i = blockIdx.x;
  const int t = threadIdx.x;
  const float4* row4 = (const float4*)(x + (size_t)i * DIM);
  float4 u = row4[2 * t], v = row4[2 * t + 1];
  float a[8] = {u.x, u.y, u.z, u.w, v.x, v.y, v.z, v.w};

  double s = 0.0;
#pragma unroll
  for (int j = 0; j < 8; ++j) s += (double)a[j] * (double)a[j];
#pragma unroll
  for (int off = 32; off > 0; off >>= 1) s += __shfl_down(s, off, 64);
  if (t == 0) sq[i] = (float)s;

  ushort h[8], m8[8], l8[8];
#pragma unroll
  for (int j = 0; j < 8; ++j) {
    float f = a[j];
    ushort hb = bf16rn(f);
    float hf = __uint_as_float(((uint32_t)hb) << 16);
    float r1 = f - hf;                 // exact in f32
    ushort mb = bf16rn(r1);
    float mf = __uint_as_float(((uint32_t)mb) << 16);
    float r2 = r1 - mf;                // exact in f32
    h[j] = hb; m8[j] = mb; l8[j] = bf16rn(r2);
  }
  const int q = i * 128 + t * 2;
  ((ushort4*)xs)[q]                = (ushort4){h[0], h[1], h[2], h[3]};
  ((ushort4*)xs)[q + 1]            = (ushort4){h[4], h[5], h[6], h[7]};
  ((ushort4*)(xs + NP))[q]         = (ushort4){m8[0], m8[1], m8[2], m8[3]};
  ((ushort4*)(xs + NP))[q + 1]     = (ushort4){m8[4], m8[5], m8[6], m8[7]};
  ((ushort4*)(xs + 2 * NP))[q]     = (ushort4){l8[0], l8[1], l8[2], l8[3]};
  ((ushort4*)(xs + 2 * NP))[q + 1] = (ushort4){l8[4], l8[5], l8[6], l8[7]};
}

// ---------------- kernel 1: upper-triangle mask; 128x64-tile fused 3-plane MFMA Gram (R10 exact) ----------------
#define BK 32
#define NTILES (DIM / BK)   // 16

__device__ __forceinline__ void gload_lds16(const ushort* g, ushort* l) {
  __builtin_amdgcn_global_load_lds((__attribute__((address_space(1))) void*)(ushort*)g,
                                   (__attribute__((address_space(3))) void*)l, 16, 0, 0);
}

__global__ __launch_bounds__(256) void gram_kernel(const ushort* __restrict__ xs,
                                                   const float* __restrict__ sq,
                                                   uint32_t* __restrict__ mask) {
  __shared__ __align__(1024) ushort SA[3][128 * BK];   // 24 KB
  __shared__ __align__(1024) ushort SB[3][64 * BK];    // 12 KB
  __shared__ uint32_t smask[128][2];                   // 1 KB

  // XCD-aware bijective swizzle: 1056 = 8 x 132
  const int tblk = (blockIdx.x & 7) * 132 + (blockIdx.x >> 3);
  // block map: tblk -> (bi, cj): row-panel bi (128 rows), col-panel cj (64 cols), cj >= 2*bi
  int bi = (int)((65.0 - sqrt(4225.0 - 4.0 * (double)tblk)) * 0.5);
  while ((bi + 1) * (65 - (bi + 1)) <= tblk) ++bi;
  while (bi * (65 - bi) > tblk) --bi;
  const int cj = 2 * bi + (tblk - bi * (65 - bi));
  const int i0 = bi * 128, c0 = cj * 64;

  const int tid = threadIdx.x;
  const int w = tid >> 6, l = tid & 63;
  const int wr = w >> 1, wc = w & 1;               // wave covers 64x32 output

  ((uint32_t*)smask)[tid] = 0u;                    // 256 words exactly

  f32x4 acc[4][2] = {};

  const int rowA = w * 32 + (l >> 2);
  const int rowB = w * 16 + (l >> 2);
  const int e0 = (((l & 3) ^ ((l >> 3) & 3)) << 3);   // swizzled source col (ushorts)
  const ushort* asrc = xs + (size_t)(i0 + rowA) * DIM + e0;
  const ushort* bsrc = xs + (size_t)(c0 + rowB) * DIM + e0;

  const int sl = (((l >> 4) ^ ((l >> 1) & 3)) << 3);
  const int abase = (wr * 64 + (l & 15)) * BK + sl;
  const int bbase = (wc * 32 + (l & 15)) * BK + sl;

#define STAGE(k0) { \
  _Pragma("unroll") for (int p_ = 0; p_ < 3; ++p_) { \
    const ushort* ap_ = asrc + (size_t)p_ * NP + (k0); \
    gload_lds16(ap_,            &SA[p_][w * 1024]); \
    gload_lds16(ap_ + 16 * DIM, &SA[p_][w * 1024 + 512]); \
    gload_lds16(bsrc + (size_t)p_ * NP + (k0), &SB[p_][w * 512]); } }

#define RDA(frag, p) { \
  _Pragma("unroll") for (int q_ = 0; q_ < 4; ++q_) \
    frag[q_] = *(const bf16x8*)(&SA[p][abase + q_ * 16 * BK]); }

#define RDB(frag, p) { \
  _Pragma("unroll") for (int q_ = 0; q_ < 2; ++q_) \
    frag[q_] = *(const bf16x8*)(&SB[p][bbase + q_ * 16 * BK]); }

#define MM(A_, B_) { \
  _Pragma("unroll") for (int m_ = 0; m_ < 4; ++m_) \
  _Pragma("unroll") for (int n_ = 0; n_ < 2; ++n_) \
    acc[m_][n_] = __builtin_amdgcn_mfma_f32_16x16x32_bf16(A_[m_], B_[n_], acc[m_][n_], 0, 0, 0); }

  STAGE(0);
#pragma unroll 1
  for (int ks = 0; ks < NTILES; ++ks) {
    __syncthreads();                      // drains vmcnt(0): STAGE(ks) landed in LDS
    bf16x8 a0[4], a1[4], a2[4], b0[2], b1[2], b2[2];
    // interleaved reads/MFMAs; per-element accumulation order: hh, hm, hl, mh, mm, lh
    RDA(a0, 0); RDB(b0, 0);
    MM(a0, b0);
    RDB(b1, 1);
    MM(a0, b1);
    RDB(b2, 2);
    MM(a0, b2);
    RDA(a1, 1);
    MM(a1, b0);
    RDA(a2, 2);
    __syncthreads();                      // all waves' LDS reads done; LDS reusable
    if (ks + 1 < NTILES) STAGE((ks + 1) * BK);   // overwrite under the last 16 MFMAs
    MM(a1, b1);
    MM(a2, b0);
  }
#undef STAGE
#undef RDA
#undef RDB
#undef MM

  __syncthreads();

  // epilogue: dist2 -> validity bits (mirror reference f32 op order)
#pragma unroll
  for (int m = 0; m < 4; ++m) {
    const int gi_base = i0 + wr * 64 + m * 16;
#pragma unroll
    for (int n = 0; n < 2; ++n) {
      const int gc = c0 + wc * 32 + n * 16 + (l & 15);
      const float sqc = sq[gc];
#pragma unroll
      for (int reg = 0; reg < 4; ++reg) {
        const int gi = gi_base + (l >> 4) * 4 + reg;
        float dot = acc[m][n][reg];
        float tsum = sq[gi] + sqc;
        float dist2 = tsum - 2.0f * dot;
        float d = sqrtf(dist2);
        bool v = (d < 1.4f) && ((gi >> 3) != (gc >> 3));
        unsigned long long b = __ballot(v);
        if (l < 4) {
          uint32_t chunk = (uint32_t)((b >> (16 * l)) & 0xFFFFull);
          int rowL = wr * 64 + m * 16 + 4 * l + reg;
          atomicOr(&smask[rowL][wc], chunk << (16 * n));
        }
      }
    }
  }
  __syncthreads();
  {
    int row = tid >> 1, wrd = tid & 1;
    mask[(size_t)(i0 + row) * MASKW + cj * 2 + wrd] = smask[row][wrd];
  }
}

// ---------------- kernel 1b: mirror upper-triangle mask blocks to lower triangle ----------------
__global__ __launch_bounds__(256) void mirror_kernel(uint32_t* __restrict__ mask) {
  const int t = blockIdx.x;                     // 0..495 : pairs bi < bj (128-blocks)
  int bi = (int)((63.0 - sqrt(3969.0 - 8.0 * (double)t)) * 0.5);
  while ((63 * (bi + 1) - (bi + 1) * (bi + 1)) / 2 <= t) ++bi;
  while ((63 * bi - bi * bi) / 2 > t) --bi;
  const int bj = bi + 1 + (t - (63 * bi - bi * bi) / 2);

  const int grp = threadIdx.x >> 5;             // 8 groups of 32 lanes
  const int lane = threadIdx.x & 31;

  for (int sb = grp; sb < 16; sb += 8) {
    const int sr = sb >> 2, sc = sb & 3;
    uint32_t x = mask[(size_t)(bi * 128 + sr * 32 + lane) * MASKW + bj * 4 + sc];
    uint32_t m = 0x0000FFFFu;
#pragma unroll
    for (int s = 16; s; s >>= 1) {
      uint32_t y = (uint32_t)__shfl_xor((int)x, s, 64);
      x = (lane & s) ? (((y >> s) & m) | (x & ~m))
                     : ((x & m) | ((y & m) << s));
      m ^= (m << (s >> 1));
    }
    mask[(size_t)(bj * 128 + sc * 32 + lane) * MASKW + bi * 4 + sr] = x;
  }
}

// ---------------- kernel 2: FUSED sample+assemble. One block per row i:
//  compact mask row -> 7 bit-exact draws (identical code to prior sample_kernel) ->
//  write all outputs owned by i: a_idx[7i..7i+6], 7 x[a] rows, 7 x[p] rows, 7 x[n] rows, x row.
#define B1F ((size_t)NDRAW)                         // a_idx floats
#define B2F (B1F + (size_t)NDRAW * DIM)             // after x[a]
#define B3F (B2F + (size_t)NDRAW * DIM)             // after x[p]
#define B4F (B3F + (size_t)NDRAW * DIM)             // after x[n]

__global__ __launch_bounds__(256) void fused_kernel(const float* __restrict__ x,
                                                    const uint32_t* __restrict__ mask,
                                                    float* __restrict__ out) {
  const int i = blockIdx.x;
  const int t = threadIdx.x;
  const int w = t >> 6, l = t & 63;

  __shared__ uint32_t m[MASKW];
  __shared__ int cnt[MASKW];
  __shared__ ushort clist[N_PTS];
  __shared__ unsigned long long red[4][KM1];
  __shared__ int nn[KM1];

  if (t < MASKW) m[t] = mask[(size_t)i * MASKW + t];
  __syncthreads();

  if (t < MASKW) cnt[t] = __popc(m[t]);
  __syncthreads();
  for (int s = 1; s < MASKW; s <<= 1) {
    int v = 0;
    if (t < MASKW) { v = cnt[t]; if (t >= s) v += cnt[t - s]; }
    __syncthreads();
    if (t < MASKW) cnt[t] = v;
    __syncthreads();
  }
  if (t < MASKW) {
    uint32_t mw = m[t];
    int off = cnt[t] - __popc(mw);
    int base_c = t << 5;
    while (mw) {
      int b = __ffs(mw) - 1;
      mw &= mw - 1;
      clist[off++] = (ushort)(base_c + b);
    }
  }
  __syncthreads();
  const int n = cnt[MASKW - 1];

  unsigned long long best[KM1];
#pragma unroll
  for (int j = 0; j < KM1; ++j) best[j] = 0ull;

  if (n > 0) {
    for (int q = t; q < n; q += 256) {
      const uint32_t c = clist[q];
#pragma unroll
      for (int j = 0; j < KM1; ++j) {
        const uint32_t ctr = ((uint32_t)(((j << 12) + i)) << 12) + c;   // r*4096+c
        uint32_t key = threefry_bits(0u, ctr) >> 9;
        unsigned long long p = ((unsigned long long)key << 12) | (unsigned long long)(4095u - c);
        if (p > best[j]) best[j] = p;
      }
    }
  } else {
    for (int c = t; c < N_PTS; c += 256) {
#pragma unroll
      for (int j = 0; j < KM1; ++j) {
        const uint32_t ctr = ((uint32_t)(((j << 12) + i)) << 12) + (uint32_t)c;
        uint32_t key = threefry_bits(0u, ctr) >> 9;
        unsigned long long p = ((unsigned long long)key << 12) | (unsigned long long)(4095u - c);
        if (p > best[j]) best[j] = p;
      }
    }
  }

#pragma unroll
  for (int j = 0; j < KM1; ++j) {
    unsigned long long b = best[j];
#pragma unroll
    for (int off = 32; off > 0; off >>= 1) {
      unsigned long long o = __shfl_down(b, off, 64);
      if (o > b) b = o;
    }
    if (l == 0) red[w][j] = b;
  }
  __syncthreads();
  if (t < KM1) {
    unsigned long long b = red[0][t];
#pragma unroll
    for (int wv = 1; wv < 4; ++wv) if (red[wv][t] > b) b = red[wv][t];
    nn[t] = 4095 - (int)(b & 0xFFFull);
  }
  __syncthreads();

  // ---- output phase (all stores coalesced: 256 threads x float2 = one 2KB row) ----
  const int s = i & 7, bs = i & ~7;
  const float2 xi = ((const float2*)(x + (size_t)i * DIM))[t];   // x[i] row, reused 8x

  if (t < KM1) out[(size_t)7 * i + t] = (float)i;                // a_idx

#pragma unroll
  for (int jj = 0; jj < KM1; ++jj)                               // x[a] rows (all = x[i])
    ((float2*)(out + B1F + (size_t)(7 * i + jj) * DIM))[t] = xi;
  ((float2*)(out + B4F + (size_t)i * DIM))[t] = xi;              // x row

#pragma unroll
  for (int jj = 0; jj < KM1; ++jj) {                             // x[p] rows
    const int src = bs + jj + (jj >= s ? 1 : 0);
    const float2 v = ((const float2*)(x + (size_t)src * DIM))[t];
    ((float2*)(out + B2F + (size_t)(7 * i + jj) * DIM))[t] = v;
  }
#pragma unroll
  for (int jj = 0; jj < KM1; ++jj) {                             // x[n] rows
    const int src = nn[jj];
    const float2 v = ((const float2*)(x + (size_t)src * DIM))[t];
    ((float2*)(out + B3F + (size_t)(7 * i + jj) * DIM))[t] = v;
  }
}

// ---------------- launch ----------------
extern "C" void kernel_launch(void* const* d_in, const int* in_sizes, int n_in,
                              void* d_out, int out_size, void* d_ws, size_t ws_size,
                              hipStream_t stream) {
  const float* x = (const float*)d_in[0];
  float* out = (float*)d_out;

  uint8_t* ws = (uint8_t*)d_ws;
  uint32_t* mask = (uint32_t*)ws;                                          // 2 MiB
  float* sq = (float*)(ws + (size_t)N_PTS * MASKW * 4);                    // 16 KiB

  // bf16 split planes live in d_out (184 MB) — fully overwritten by fused_kernel later
  ushort* xs = (ushort*)d_out;

  split_kernel<<<N_PTS, 64, 0, stream>>>(x, xs, sq);
  gram_kernel<<<1056, 256, 0, stream>>>(xs, sq, mask);
  mirror_kernel<<<496, 256, 0, stream>>>(mask);
  fused_kernel<<<N_PTS, 256, 0, stream>>>(x, mask, out);
}